// Round 9
// baseline (216.821 us; speedup 1.0000x reference)
//
#include <hip/hip_runtime.h>
#include <hip/hip_bf16.h>

#define NB 2
#define NS 2048
#define NE 1024
#define NH 16
#define HD 64

typedef __hip_bfloat16 bf16;
typedef __attribute__((ext_vector_type(8))) short bf16x8;
typedef __attribute__((ext_vector_type(4))) float f32x4;

typedef __attribute__((address_space(3))) void* lds_p;
typedef const __attribute__((address_space(1))) void* glb_p;

#define MFMA16(a, b, c) __builtin_amdgcn_mfma_f32_16x16x32_bf16((a), (b), (c), 0, 0, 0)

__device__ __forceinline__ void gl_lds16(const void* g, void* l) {
    __builtin_amdgcn_global_load_lds((glb_p)g, (lds_p)l, 16, 0, 0);
}

__device__ __forceinline__ bf16x8 ldv8(const bf16* p) { return *(const bf16x8*)p; }

__device__ __forceinline__ float bf16raw2f(unsigned short v) {
    union { unsigned u; float f; } c;
    c.u = ((unsigned)v) << 16;
    return c.f;
}

// ---------------- merged cast f32 -> bf16 (vectorized, 1 launch) ----------------
__global__ __launch_bounds__(256) void cast3_k(const float* __restrict__ x,
                                               const float* __restrict__ wqkv,
                                               const float* __restrict__ wo,
                                               bf16* __restrict__ xb,
                                               bf16* __restrict__ wqkvb,
                                               bf16* __restrict__ wob) {
    const int n_x = NB * NS * NE / 4;
    const int n_q = 3 * NE * NE / 4;
    const int n_o = NE * NE / 4;
    int i = blockIdx.x * 256 + threadIdx.x;
    const float* in;
    bf16* out;
    int j;
    if (i < n_x) {
        in = x; out = xb; j = i;
    } else if (i < n_x + n_q) {
        in = wqkv; out = wqkvb; j = i - n_x;
    } else if (i < n_x + n_q + n_o) {
        in = wo; out = wob; j = i - n_x - n_q;
    } else {
        return;
    }
    float4 v = ((const float4*)in)[j];
    union { ushort4 u; bf16 b[4]; } pk;
    pk.b[0] = __float2bfloat16(v.x);
    pk.b[1] = __float2bfloat16(v.y);
    pk.b[2] = __float2bfloat16(v.z);
    pk.b[3] = __float2bfloat16(v.w);
    ((ushort4*)out)[j] = pk.u;
}

// ---------------- QKV GEMM: C[t,f] = sum_e x[t,e] * Wqkv[f,e] + bqkv[f] ----------------
__global__ __launch_bounds__(256) void qkv_gemm(const bf16* __restrict__ A,
                                                const bf16* __restrict__ Bm,
                                                const float* __restrict__ bqkv,
                                                bf16* __restrict__ Qb, bf16* __restrict__ Kb,
                                                bf16* __restrict__ Vtb) {
    __shared__ bf16 As[128 * 32];
    __shared__ bf16 Bs[128 * 32];
    const int brow = blockIdx.x * 128;
    const int bcol = blockIdx.y * 128;
    const int t = threadIdx.x;
    const int w = t >> 6, lane = t & 63;
    const int wr = (w >> 1) * 64, wc = (w & 1) * 64;
    const int lr = lane & 15, lh = lane >> 4;
    const int K = 1024;

    f32x4 acc[4][4];
#pragma unroll
    for (int m = 0; m < 4; ++m)
#pragma unroll
        for (int n = 0; n < 4; ++n) acc[m][n] = (f32x4){0.f, 0.f, 0.f, 0.f};

    const bf16* ga0 = A + (size_t)(brow + (t >> 2)) * K + (t & 3) * 8;
    const bf16* ga1 = A + (size_t)(brow + 64 + (t >> 2)) * K + (t & 3) * 8;
    const bf16* gb0 = Bm + (size_t)(bcol + (t >> 2)) * K + (t & 3) * 8;
    const bf16* gb1 = Bm + (size_t)(bcol + 64 + (t >> 2)) * K + (t & 3) * 8;
    bf16* la0 = As + t * 8;
    bf16* la1 = As + 2048 + t * 8;
    bf16* lb0 = Bs + t * 8;
    bf16* lb1 = Bs + 2048 + t * 8;

    for (int kt = 0; kt < K; kt += 32) {
        gl_lds16(ga0 + kt, la0);
        gl_lds16(ga1 + kt, la1);
        gl_lds16(gb0 + kt, lb0);
        gl_lds16(gb1 + kt, lb1);
        __syncthreads();
        bf16x8 af[4], bfv[4];
#pragma unroll
        for (int m = 0; m < 4; ++m) af[m] = ldv8(&As[(wr + m * 16 + lr) * 32 + lh * 8]);
#pragma unroll
        for (int n = 0; n < 4; ++n) bfv[n] = ldv8(&Bs[(wc + n * 16 + lr) * 32 + lh * 8]);
#pragma unroll
        for (int m = 0; m < 4; ++m)
#pragma unroll
            for (int n = 0; n < 4; ++n) acc[m][n] = MFMA16(af[m], bfv[n], acc[m][n]);
        __syncthreads();
    }

    // epilogue: f -> (h, which, d); which: 0=Q 1=K 2=V
#pragma unroll
    for (int n = 0; n < 4; ++n) {
        const int col = bcol + wc + n * 16 + lr;
        const int h = col / 192;
        const int r = col - h * 192;
        const int wh = r >> 6;
        const int d = r & 63;
        const float bq = bqkv[col];
#pragma unroll
        for (int m = 0; m < 4; ++m) {
            const int row0 = brow + wr + m * 16 + lh * 4;  // token base; i adds 0..3
            const int b = row0 >> 11;
            const int s0 = row0 & 2047;
            const size_t hb = (size_t)(b * NH + h) * (NS * HD);
            if (wh == 2) {
                alignas(8) bf16 tmp[4];
#pragma unroll
                for (int i = 0; i < 4; ++i) tmp[i] = __float2bfloat16(acc[m][n][i] + bq);
                *(ushort4*)(Vtb + hb + (size_t)d * NS + s0) = *(const ushort4*)tmp;
            } else {
                bf16* dst = (wh == 0 ? Qb : Kb) + hb + (size_t)s0 * HD + d;
#pragma unroll
                for (int i = 0; i < 4; ++i) dst[(size_t)i * HD] = __float2bfloat16(acc[m][n][i] + bq);
            }
        }
    }
}

// ---------------- fused attention: row-contiguous bias via Ps staging ----------------
// 1024 blocks (XCD swizzle), 4 waves x 16 q-rows, one bh per block. LDS 40KB -> 4/CU.
// Bias path: f32 loads in 256B row-contiguous segments (full HBM lines) two tiles
// ahead -> cvt bf16 -> stashed in the wave's Ps slot (P overwrites it after the
// softmax reads it; per-wave LDS ops are in-order so read-then-write is safe).
// vmcnt(4) barrier keeps bias(tt+2) in flight - stream never drained.
__global__ __launch_bounds__(256, 4) void attn_k(const bf16* __restrict__ Qb,
                                                 const bf16* __restrict__ Kb,
                                                 const bf16* __restrict__ Vtb,
                                                 const float* __restrict__ bias,
                                                 bf16* __restrict__ valsb) {
    const int L = blockIdx.x;
    const int xcd = L & 7, kk = L >> 3;
    const int bh = (xcd << 2) | (kk >> 5);   // 4 bh per XCD (K/V L2-resident)
    const int q0 = (kk & 31) * 64;
    const int t = threadIdx.x;
    const int w = t >> 6, lane = t & 63;
    const int lr = lane & 15, lh = lane >> 4;

    __shared__ bf16 Kls[2][64 * 64];   // 16 KB
    __shared__ bf16 Vls[2][64 * 64];   // 16 KB
    __shared__ bf16 Ps[4][16 * 64];    // 8 KB: bias(tt) then P(tt), XOR-swizzled 16B units

    const bf16* Qp = Qb + (size_t)bh * NS * HD;
    const bf16* Kp = Kb + (size_t)bh * NS * HD;
    const bf16* Vp = Vtb + (size_t)bh * HD * NS;

    const int qw = q0 + w * 16;
    bf16x8 qf0 = ldv8(&Qp[(qw + lr) * HD + lh * 8]);
    bf16x8 qf1 = ldv8(&Qp[(qw + lr) * HD + 32 + lh * 8]);

    // row-contiguous bias base: group g = lh rows, 16 lanes x float4 = 256B per row
    const float* Bst = bias + (size_t)bh * NS * NS + (size_t)(qw + lh) * NS + lr * 4;

    // staging geometry (XOR-swizzled source, linear LDS dest; rule #21)
    const int srow0 = t >> 3;
    const int sce0 = ((t & 7) * 8) ^ ((srow0 & 7) << 3);
    const int srow1 = srow0 + 32;
    const int sce1 = ((t & 7) * 8) ^ ((srow1 & 7) << 3);

    f32x4 acc_o[4];
    float rowsum = 0.f;
#pragma unroll
    for (int n = 0; n < 4; ++n) acc_o[n] = (f32x4){0.f, 0.f, 0.f, 0.f};

    const float C1 = 0.18033688011112042f;  // 0.125 * log2(e)
    const float C2 = 7.2134752044448170f;   // 5 * log2(e)

    // read-side swizzled column offsets (K/V: row = n*16+lr => row&7 = lr&7)
    const int rswz = (lr & 7) << 3;
    const int ce0 = (lh * 8) ^ rswz;
    const int ce1 = (32 + lh * 8) ^ rswz;
    const int pswz = (lr & 7) << 3;  // Ps swizzle for softmax-row (lr) access

    float4 vrA[4], vrB[4];

    // stash: rows n*4+lh, col lr*4 (ushort4 stays within one 8-elem swizzle unit)
#define BIAS_STASH(VR)                                                                 \
    _Pragma("unroll") for (int n = 0; n < 4; ++n) {                                    \
        union { ushort4 u; bf16 b[4]; } pk;                                            \
        pk.b[0] = __float2bfloat16(VR[n].x);                                           \
        pk.b[1] = __float2bfloat16(VR[n].y);                                           \
        pk.b[2] = __float2bfloat16(VR[n].z);                                           \
        pk.b[3] = __float2bfloat16(VR[n].w);                                           \
        const int rr = n * 4 + lh;                                                     \
        *(ushort4*)&Ps[w][rr * 64 + ((lr * 4) ^ ((rr & 7) << 3))] = pk.u;              \
    }

    // -------- prologue: gl_lds(0) | bias(0)->vrA | bias(1)->vrB | stash(0) | bar
    gl_lds16(Kp + (size_t)srow0 * HD + sce0, &Kls[0][t * 8]);
    gl_lds16(Kp + (size_t)srow1 * HD + sce1, &Kls[0][2048 + t * 8]);
    gl_lds16(Vp + (size_t)srow0 * NS + sce0, &Vls[0][t * 8]);
    gl_lds16(Vp + (size_t)srow1 * NS + sce1, &Vls[0][2048 + t * 8]);
    __builtin_amdgcn_sched_barrier(0);
#pragma unroll
    for (int n = 0; n < 4; ++n) vrA[n] = *(const float4*)(Bst + (size_t)(n * 4) * NS);
    __builtin_amdgcn_sched_barrier(0);
#pragma unroll
    for (int n = 0; n < 4; ++n) vrB[n] = *(const float4*)(Bst + (size_t)(n * 4) * NS + 64);
    __builtin_amdgcn_sched_barrier(0);
    BIAS_STASH(vrA)  // auto-waits bias(0); gl_lds(0) older -> also done
    __builtin_amdgcn_sched_barrier(0);
    __builtin_amdgcn_s_barrier();
    __builtin_amdgcn_sched_barrier(0);

#define ATTN_COMPUTE(CUR)                                                             \
    {                                                                                 \
        const bf16* Kc = &Kls[CUR][0];                                                \
        f32x4 s[4];                                                                   \
        ushort4 bu[4];                                                                \
        _Pragma("unroll") for (int n = 0; n < 4; ++n)                                 \
            bu[n] = *(const ushort4*)&Ps[w][lr * 64 + ((n * 16 + lh * 4) ^ pswz)];    \
        _Pragma("unroll") for (int n = 0; n < 4; ++n) {                               \
            bf16x8 k0 = ldv8(&Kc[(n * 16 + lr) * 64 + ce0]);                          \
            bf16x8 k1 = ldv8(&Kc[(n * 16 + lr) * 64 + ce1]);                          \
            s[n] = (f32x4){0.f, 0.f, 0.f, 0.f};                                       \
            s[n] = MFMA16(k0, qf0, s[n]);                                             \
            s[n] = MFMA16(k1, qf1, s[n]);                                             \
        }                                                                             \
        _Pragma("unroll") for (int n = 0; n < 4; ++n) {                               \
            union { ushort4 u; bf16 b[4]; } pk;                                       \
            float bb[4] = {bf16raw2f(bu[n].x), bf16raw2f(bu[n].y),                    \
                           bf16raw2f(bu[n].z), bf16raw2f(bu[n].w)};                   \
            _Pragma("unroll") for (int i = 0; i < 4; ++i) {                           \
                float xv = (s[n][i] + bb[i]) * C1;                                    \
                xv = fminf(fmaxf(xv, -C2), C2);                                       \
                float p = exp2f(xv);                                                  \
                rowsum += p;                                                          \
                pk.b[i] = __float2bfloat16(p);                                        \
            }                                                                         \
            *(ushort4*)&Ps[w][lr * 64 + ((n * 16 + lh * 4) ^ pswz)] = pk.u;           \
        }                                                                             \
        bf16x8 pa0 = ldv8(&Ps[w][lr * 64 + ((lh * 8) ^ pswz)]);                       \
        bf16x8 pa1 = ldv8(&Ps[w][lr * 64 + (((32 + lh * 8)) ^ pswz)]);                \
        const bf16* Vc = &Vls[CUR][0];                                                \
        _Pragma("unroll") for (int n = 0; n < 4; ++n) {                               \
            bf16x8 v0 = ldv8(&Vc[(n * 16 + lr) * 64 + ce0]);                          \
            bf16x8 v1 = ldv8(&Vc[(n * 16 + lr) * 64 + ce1]);                          \
            acc_o[n] = MFMA16(pa0, v0, acc_o[n]);                                     \
            acc_o[n] = MFMA16(pa1, v1, acc_o[n]);                                     \
        }                                                                             \
    }

    // step tt: gl_lds(tt+1) | issue bias(tt+2)->VRN | compute(tt) | stash VRC=bias(tt+1)
    //          | vmcnt(4) (gl_lds done, bias(tt+2) in flight) | barrier
#define TILESTEP(CUR, VRC, VRN, KTN)                                                  \
    {                                                                                 \
        bf16* Kd = &Kls[(CUR) ^ 1][0];                                                \
        bf16* Vd = &Vls[(CUR) ^ 1][0];                                                \
        gl_lds16(Kp + (size_t)((KTN) + srow0) * HD + sce0, Kd + t * 8);               \
        gl_lds16(Kp + (size_t)((KTN) + srow1) * HD + sce1, Kd + 2048 + t * 8);        \
        gl_lds16(Vp + (size_t)srow0 * NS + (KTN) + sce0, Vd + t * 8);                 \
        gl_lds16(Vp + (size_t)srow1 * NS + (KTN) + sce1, Vd + 2048 + t * 8);          \
        __builtin_amdgcn_sched_barrier(0);                                            \
        _Pragma("unroll") for (int n = 0; n < 4; ++n)                                 \
            VRN[n] = *(const float4*)(Bst + (size_t)(n * 4) * NS + (KTN) + 64);       \
        __builtin_amdgcn_sched_barrier(0);                                            \
        ATTN_COMPUTE(CUR)                                                             \
        __builtin_amdgcn_sched_barrier(0);                                            \
        BIAS_STASH(VRC)                                                               \
        __builtin_amdgcn_sched_barrier(0);                                            \
        asm volatile("s_waitcnt vmcnt(4)" ::: "memory");                              \
        __builtin_amdgcn_sched_barrier(0);                                            \
        __builtin_amdgcn_s_barrier();                                                 \
        __builtin_amdgcn_sched_barrier(0);                                            \
    }

    // -------- main loop: tiles 0..29, unrolled x2 for static register naming --------
    for (int it = 0; it < 15; ++it) {
        const int tt = it * 2;
        TILESTEP(0, vrB, vrA, (tt + 1) * 64)   // computes tt;   stash bias(tt+1)=vrB
        TILESTEP(1, vrA, vrB, (tt + 2) * 64)   // computes tt+1; stash bias(tt+2)=vrA
    }

    // -------- tile 30: stage tile 31, stash bias(31)=vrB, full drain --------
    {
        const int ktn = 31 * 64;
        bf16* Kd = &Kls[1][0];
        bf16* Vd = &Vls[1][0];
        gl_lds16(Kp + (size_t)(ktn + srow0) * HD + sce0, Kd + t * 8);
        gl_lds16(Kp + (size_t)(ktn + srow1) * HD + sce1, Kd + 2048 + t * 8);
        gl_lds16(Vp + (size_t)srow0 * NS + ktn + sce0, Vd + t * 8);
        gl_lds16(Vp + (size_t)srow1 * NS + ktn + sce1, Vd + 2048 + t * 8);
        __builtin_amdgcn_sched_barrier(0);
        ATTN_COMPUTE(0)
        __builtin_amdgcn_sched_barrier(0);
        BIAS_STASH(vrB)
        __builtin_amdgcn_sched_barrier(0);
        asm volatile("s_waitcnt vmcnt(0)" ::: "memory");
        __builtin_amdgcn_sched_barrier(0);
        __builtin_amdgcn_s_barrier();
        __builtin_amdgcn_sched_barrier(0);
    }
    // -------- tile 31: compute only --------
    ATTN_COMPUTE(1)
#undef TILESTEP
#undef ATTN_COMPUTE
#undef BIAS_STASH

    // rowsum for q = qw + (lane&15): reduce over the 4 lh-groups
    rowsum += __shfl_xor(rowsum, 16, 64);
    rowsum += __shfl_xor(rowsum, 32, 64);
    // redistribute: output rows are q = qw + lh*4 + i (held at lane lh*4+i)
    float inv[4];
#pragma unroll
    for (int i = 0; i < 4; ++i) inv[i] = 1.0f / __shfl(rowsum, lh * 4 + i, 64);

    const int b = bh >> 4, h = bh & 15;
#pragma unroll
    for (int n = 0; n < 4; ++n) {
#pragma unroll
        for (int i = 0; i < 4; ++i) {
            const int qrow = qw + lh * 4 + i;
            valsb[(size_t)(b * NS + qrow) * NE + h * HD + n * 16 + lr] =
                __float2bfloat16(acc_o[n][i] * inv[i]);
        }
    }
}

// ---------------- out GEMM: 128x64 tiles (512 blocks = 2/CU) ----------------
__global__ __launch_bounds__(256) void out_gemm(const bf16* __restrict__ A,
                                                const bf16* __restrict__ Bm,
                                                const float* __restrict__ bo,
                                                float* __restrict__ out) {
    __shared__ bf16 As[128 * 32];
    __shared__ bf16 Bs[64 * 32];
    const int brow = blockIdx.x * 128;
    const int bcol = blockIdx.y * 64;
    const int t = threadIdx.x;
    const int w = t >> 6, lane = t & 63;
    const int wr = (w >> 1) * 64, wc = (w & 1) * 32;
    const int lr = lane & 15, lh = lane >> 4;
    const int K = 1024;

    f32x4 acc[4][2];
#pragma unroll
    for (int m = 0; m < 4; ++m)
#pragma unroll
        for (int n = 0; n < 2; ++n) acc[m][n] = (f32x4){0.f, 0.f, 0.f, 0.f};

    const bf16* ga0 = A + (size_t)(brow + (t >> 2)) * K + (t & 3) * 8;
    const bf16* ga1 = A + (size_t)(brow + 64 + (t >> 2)) * K + (t & 3) * 8;
    const bf16* gb0 = Bm + (size_t)(bcol + (t >> 2)) * K + (t & 3) * 8;
    bf16* la0 = As + t * 8;
    bf16* la1 = As + 2048 + t * 8;
    bf16* lb0 = Bs + t * 8;

    for (int kt = 0; kt < K; kt += 32) {
        gl_lds16(ga0 + kt, la0);
        gl_lds16(ga1 + kt, la1);
        gl_lds16(gb0 + kt, lb0);
        __syncthreads();
        bf16x8 af[4], bfv[2];
#pragma unroll
        for (int m = 0; m < 4; ++m) af[m] = ldv8(&As[(wr + m * 16 + lr) * 32 + lh * 8]);
#pragma unroll
        for (int n = 0; n < 2; ++n) bfv[n] = ldv8(&Bs[(wc + n * 16 + lr) * 32 + lh * 8]);
#pragma unroll
        for (int m = 0; m < 4; ++m)
#pragma unroll
            for (int n = 0; n < 2; ++n) acc[m][n] = MFMA16(af[m], bfv[n], acc[m][n]);
        __syncthreads();
    }

#pragma unroll
    for (int n = 0; n < 2; ++n) {
        const int col = bcol + wc + n * 16 + lr;
        const float bv = bo[col];
#pragma unroll
        for (int m = 0; m < 4; ++m) {
            const int row0 = brow + wr + m * 16 + lh * 4;
#pragma unroll
            for (int i = 0; i < 4; ++i) out[(size_t)(row0 + i) * NE + col] = acc[m][n][i] + bv;
        }
    }
}

extern "C" void kernel_launch(void* const* d_in, const int* in_sizes, int n_in,
                              void* d_out, int out_size, void* d_ws, size_t ws_size,
                              hipStream_t stream) {
    const float* x = (const float*)d_in[0];
    const float* attn_bias = (const float*)d_in[1];
    const float* Wqkv = (const float*)d_in[2];
    const float* bqkv = (const float*)d_in[3];
    const float* Wo = (const float*)d_in[4];
    const float* bo = (const float*)d_in[5];
    float* out = (float*)d_out;

    char* ws = (char*)d_ws;
    bf16* xb = (bf16*)(ws);                      // 8 MiB  [4096,1024]
    bf16* Wqkvb = (bf16*)(ws + (8u << 20));      // 6 MiB  [3072,1024]
    bf16* Wob = (bf16*)(ws + (14u << 20));       // 2 MiB  [1024,1024]
    bf16* Qb = (bf16*)(ws + (16u << 20));        // 8 MiB  [B,H,S,HD]
    bf16* Kb = (bf16*)(ws + (24u << 20));        // 8 MiB  [B,H,S,HD]
    bf16* Vtb = (bf16*)(ws + (32u << 20));       // 8 MiB  [B,H,HD,S]
    bf16* valsb = (bf16*)(ws + (40u << 20));     // 8 MiB  [B,S,H,HD]

    // merged casts (1 launch)
    cast3_k<<<8192, 256, 0, stream>>>(x, Wqkv, Wo, xb, Wqkvb, Wob);

    // QKV projection
    qkv_gemm<<<dim3(32, 24), 256, 0, stream>>>(xb, Wqkvb, bqkv, Qb, Kb, Vtb);

    // fused attention (1-D grid, XCD swizzle inside)
    attn_k<<<dim3(1024), 256, 0, stream>>>(Qb, Kb, Vtb, attn_bias, valsb);

    // output projection
    out_gemm<<<dim3(32, 16), 256, 0, stream>>>(valsb, Wob, bo, out);
}

// Round 10
// 214.330 us; speedup vs baseline: 1.0116x; 1.0116x over previous
//
#include <hip/hip_runtime.h>
#include <hip/hip_bf16.h>

#define NB 2
#define NS 2048
#define NE 1024
#define NH 16
#define HD 64

typedef __hip_bfloat16 bf16;
typedef __attribute__((ext_vector_type(8))) short bf16x8;
typedef __attribute__((ext_vector_type(4))) float f32x4;

typedef __attribute__((address_space(3))) void* lds_p;
typedef const __attribute__((address_space(1))) void* glb_p;

#define MFMA16(a, b, c) __builtin_amdgcn_mfma_f32_16x16x32_bf16((a), (b), (c), 0, 0, 0)

__device__ __forceinline__ void gl_lds16(const void* g, void* l) {
    __builtin_amdgcn_global_load_lds((glb_p)g, (lds_p)l, 16, 0, 0);
}

__device__ __forceinline__ bf16x8 ldv8(const bf16* p) { return *(const bf16x8*)p; }

// ---------------- merged cast f32 -> bf16 (vectorized, 1 launch) ----------------
__global__ __launch_bounds__(256) void cast3_k(const float* __restrict__ x,
                                               const float* __restrict__ wqkv,
                                               const float* __restrict__ wo,
                                               bf16* __restrict__ xb,
                                               bf16* __restrict__ wqkvb,
                                               bf16* __restrict__ wob) {
    const int n_x = NB * NS * NE / 4;
    const int n_q = 3 * NE * NE / 4;
    const int n_o = NE * NE / 4;
    int i = blockIdx.x * 256 + threadIdx.x;
    const float* in;
    bf16* out;
    int j;
    if (i < n_x) {
        in = x; out = xb; j = i;
    } else if (i < n_x + n_q) {
        in = wqkv; out = wqkvb; j = i - n_x;
    } else if (i < n_x + n_q + n_o) {
        in = wo; out = wob; j = i - n_x - n_q;
    } else {
        return;
    }
    float4 v = ((const float4*)in)[j];
    union { ushort4 u; bf16 b[4]; } pk;
    pk.b[0] = __float2bfloat16(v.x);
    pk.b[1] = __float2bfloat16(v.y);
    pk.b[2] = __float2bfloat16(v.z);
    pk.b[3] = __float2bfloat16(v.w);
    ((ushort4*)out)[j] = pk.u;
}

// ---------------- QKV GEMM: C[t,f] = sum_e x[t,e] * Wqkv[f,e] + bqkv[f] ----------------
__global__ __launch_bounds__(256) void qkv_gemm(const bf16* __restrict__ A,
                                                const bf16* __restrict__ Bm,
                                                const float* __restrict__ bqkv,
                                                bf16* __restrict__ Qb, bf16* __restrict__ Kb,
                                                bf16* __restrict__ Vtb) {
    __shared__ bf16 As[128 * 32];
    __shared__ bf16 Bs[128 * 32];
    const int brow = blockIdx.x * 128;
    const int bcol = blockIdx.y * 128;
    const int t = threadIdx.x;
    const int w = t >> 6, lane = t & 63;
    const int wr = (w >> 1) * 64, wc = (w & 1) * 64;
    const int lr = lane & 15, lh = lane >> 4;
    const int K = 1024;

    f32x4 acc[4][4];
#pragma unroll
    for (int m = 0; m < 4; ++m)
#pragma unroll
        for (int n = 0; n < 4; ++n) acc[m][n] = (f32x4){0.f, 0.f, 0.f, 0.f};

    const bf16* ga0 = A + (size_t)(brow + (t >> 2)) * K + (t & 3) * 8;
    const bf16* ga1 = A + (size_t)(brow + 64 + (t >> 2)) * K + (t & 3) * 8;
    const bf16* gb0 = Bm + (size_t)(bcol + (t >> 2)) * K + (t & 3) * 8;
    const bf16* gb1 = Bm + (size_t)(bcol + 64 + (t >> 2)) * K + (t & 3) * 8;
    bf16* la0 = As + t * 8;
    bf16* la1 = As + 2048 + t * 8;
    bf16* lb0 = Bs + t * 8;
    bf16* lb1 = Bs + 2048 + t * 8;

    for (int kt = 0; kt < K; kt += 32) {
        gl_lds16(ga0 + kt, la0);
        gl_lds16(ga1 + kt, la1);
        gl_lds16(gb0 + kt, lb0);
        gl_lds16(gb1 + kt, lb1);
        __syncthreads();
        bf16x8 af[4], bfv[4];
#pragma unroll
        for (int m = 0; m < 4; ++m) af[m] = ldv8(&As[(wr + m * 16 + lr) * 32 + lh * 8]);
#pragma unroll
        for (int n = 0; n < 4; ++n) bfv[n] = ldv8(&Bs[(wc + n * 16 + lr) * 32 + lh * 8]);
#pragma unroll
        for (int m = 0; m < 4; ++m)
#pragma unroll
            for (int n = 0; n < 4; ++n) acc[m][n] = MFMA16(af[m], bfv[n], acc[m][n]);
        __syncthreads();
    }

    // epilogue: f -> (h, which, d); which: 0=Q 1=K 2=V
#pragma unroll
    for (int n = 0; n < 4; ++n) {
        const int col = bcol + wc + n * 16 + lr;
        const int h = col / 192;
        const int r = col - h * 192;
        const int wh = r >> 6;
        const int d = r & 63;
        const float bq = bqkv[col];
#pragma unroll
        for (int m = 0; m < 4; ++m) {
            const int row0 = brow + wr + m * 16 + lh * 4;  // token base; i adds 0..3
            const int b = row0 >> 11;
            const int s0 = row0 & 2047;
            const size_t hb = (size_t)(b * NH + h) * (NS * HD);
            if (wh == 2) {
                alignas(8) bf16 tmp[4];
#pragma unroll
                for (int i = 0; i < 4; ++i) tmp[i] = __float2bfloat16(acc[m][n][i] + bq);
                *(ushort4*)(Vtb + hb + (size_t)d * NS + s0) = *(const ushort4*)tmp;
            } else {
                bf16* dst = (wh == 0 ? Qb : Kb) + hb + (size_t)s0 * HD + d;
#pragma unroll
                for (int i = 0; i < 4; ++i) dst[(size_t)i * HD] = __float2bfloat16(acc[m][n][i] + bq);
            }
        }
    }
}

// ---------------- fused attention: LDS K/V + counted vmcnt + 4 blocks/CU (r8) ----------------
// 1024 blocks (XCD swizzle), 4 waves x 16 q-rows, one bh per block.
// LDS exactly 40KB (Ps XOR-swizzled, no pad) -> 4 blocks/CU: all 1024 blocks
// co-resident (no tail), 16 waves/CU of outstanding bias requests.
// Per tile: [gl_lds(tt+1) x4] | compute(tt) | [bias(tt+2) x4 into just-freed set] |
// vmcnt(4) | s_barrier.  Oldest-first drain forces bias(tt+1)+gl_lds(tt+1) complete,
// keeps bias(tt+2) in flight - the bias HBM stream is never drained.
__global__ __launch_bounds__(256, 4) void attn_k(const bf16* __restrict__ Qb,
                                                 const bf16* __restrict__ Kb,
                                                 const bf16* __restrict__ Vtb,
                                                 const float* __restrict__ bias,
                                                 bf16* __restrict__ valsb) {
    const int L = blockIdx.x;
    const int xcd = L & 7, kk = L >> 3;
    const int bh = (xcd << 2) | (kk >> 5);   // 4 bh per XCD (K/V L2-resident)
    const int q0 = (kk & 31) * 64;
    const int t = threadIdx.x;
    const int w = t >> 6, lane = t & 63;
    const int lr = lane & 15, lh = lane >> 4;

    __shared__ bf16 Kls[2][64 * 64];   // 16 KB
    __shared__ bf16 Vls[2][64 * 64];   // 16 KB
    __shared__ bf16 Ps[4][16 * 64];    // 8 KB, XOR-swizzled in 16B units

    const bf16* Qp = Qb + (size_t)bh * NS * HD;
    const bf16* Kp = Kb + (size_t)bh * NS * HD;
    const bf16* Vp = Vtb + (size_t)bh * HD * NS;

    const int qw = q0 + w * 16;
    bf16x8 qf0 = ldv8(&Qp[(qw + lr) * HD + lh * 8]);
    bf16x8 qf1 = ldv8(&Qp[(qw + lr) * HD + 32 + lh * 8]);

    // per-lane bias base: row q = qw+lr, col base lh*4
    const float* Bp = bias + (size_t)bh * NS * NS + (size_t)(qw + lr) * NS + lh * 4;

    // staging geometry (XOR-swizzled source, linear LDS dest; rule #21)
    const int srow0 = t >> 3;
    const int sce0 = ((t & 7) * 8) ^ ((srow0 & 7) << 3);
    const int srow1 = srow0 + 32;
    const int sce1 = ((t & 7) * 8) ^ ((srow1 & 7) << 3);

    f32x4 acc_o[4];
    float rowsum = 0.f;
#pragma unroll
    for (int n = 0; n < 4; ++n) acc_o[n] = (f32x4){0.f, 0.f, 0.f, 0.f};

    const float C1 = 0.18033688011112042f;  // 0.125 * log2(e)
    const float C2 = 7.2134752044448170f;   // 5 * log2(e)

    // read-side swizzled column offsets (K/V: row = n*16+lr => row&7 = lr&7)
    const int rswz = (lr & 7) << 3;
    const int ce0 = (lh * 8) ^ rswz;
    const int ce1 = (32 + lh * 8) ^ rswz;
    // Ps swizzle: 16B unit index XORed with lr&7 (write ushort4 stays in-unit)
    const int pswz = (lr & 7) << 3;

    // -------- prologue: [gl_lds(0) x4] | bias(0)->bvA | bias(1)->bvB | vmcnt(8) | bar
    gl_lds16(Kp + (size_t)srow0 * HD + sce0, &Kls[0][t * 8]);
    gl_lds16(Kp + (size_t)srow1 * HD + sce1, &Kls[0][2048 + t * 8]);
    gl_lds16(Vp + (size_t)srow0 * NS + sce0, &Vls[0][t * 8]);
    gl_lds16(Vp + (size_t)srow1 * NS + sce1, &Vls[0][2048 + t * 8]);
    __builtin_amdgcn_sched_barrier(0);
    float4 bvA[4], bvB[4];
#pragma unroll
    for (int n = 0; n < 4; ++n) bvA[n] = *(const float4*)(Bp + n * 16);
    __builtin_amdgcn_sched_barrier(0);
#pragma unroll
    for (int n = 0; n < 4; ++n) bvB[n] = *(const float4*)(Bp + 64 + n * 16);
    __builtin_amdgcn_sched_barrier(0);
    asm volatile("s_waitcnt vmcnt(8)" ::: "memory");
    __builtin_amdgcn_sched_barrier(0);
    __builtin_amdgcn_s_barrier();
    __builtin_amdgcn_sched_barrier(0);

#define ATTN_COMPUTE(CUR, BV)                                                         \
    {                                                                                 \
        const bf16* Kc = &Kls[CUR][0];                                                \
        f32x4 s[4];                                                                   \
        _Pragma("unroll") for (int n = 0; n < 4; ++n) {                               \
            bf16x8 k0 = ldv8(&Kc[(n * 16 + lr) * 64 + ce0]);                          \
            bf16x8 k1 = ldv8(&Kc[(n * 16 + lr) * 64 + ce1]);                          \
            s[n] = (f32x4){0.f, 0.f, 0.f, 0.f};                                       \
            s[n] = MFMA16(k0, qf0, s[n]);                                             \
            s[n] = MFMA16(k1, qf1, s[n]);                                             \
        }                                                                             \
        _Pragma("unroll") for (int n = 0; n < 4; ++n) {                               \
            union { ushort4 u; bf16 b[4]; } pk;                                       \
            _Pragma("unroll") for (int i = 0; i < 4; ++i) {                           \
                float bb = (i == 0   ? BV[n].x                                        \
                            : i == 1 ? BV[n].y                                        \
                            : i == 2 ? BV[n].z                                        \
                                     : BV[n].w);                                      \
                float xv = (s[n][i] + bb) * C1;                                       \
                xv = fminf(fmaxf(xv, -C2), C2);                                       \
                float p = exp2f(xv);                                                  \
                rowsum += p;                                                          \
                pk.b[i] = __float2bfloat16(p);                                        \
            }                                                                         \
            *(ushort4*)&Ps[w][lr * 64 + ((n * 16 + lh * 4) ^ pswz)] = pk.u;           \
        }                                                                             \
        bf16x8 pa0 = ldv8(&Ps[w][lr * 64 + ((lh * 8) ^ pswz)]);                       \
        bf16x8 pa1 = ldv8(&Ps[w][lr * 64 + (((32 + lh * 8)) ^ pswz)]);                \
        const bf16* Vc = &Vls[CUR][0];                                                \
        _Pragma("unroll") for (int n = 0; n < 4; ++n) {                               \
            bf16x8 v0 = ldv8(&Vc[(n * 16 + lr) * 64 + ce0]);                          \
            bf16x8 v1 = ldv8(&Vc[(n * 16 + lr) * 64 + ce1]);                          \
            acc_o[n] = MFMA16(pa0, v0, acc_o[n]);                                     \
            acc_o[n] = MFMA16(pa1, v1, acc_o[n]);                                     \
        }                                                                             \
    }

    // one tile step: stage tile at KTN into buf CUR^1, compute tile CUR from bias BV,
    // then refill BV with bias(KTN+64) (consumed two tiles later).
#define TILESTEP(CUR, BV, KTN)                                                        \
    {                                                                                 \
        bf16* Kd = &Kls[(CUR) ^ 1][0];                                                \
        bf16* Vd = &Vls[(CUR) ^ 1][0];                                                \
        gl_lds16(Kp + (size_t)((KTN) + srow0) * HD + sce0, Kd + t * 8);               \
        gl_lds16(Kp + (size_t)((KTN) + srow1) * HD + sce1, Kd + 2048 + t * 8);        \
        gl_lds16(Vp + (size_t)srow0 * NS + (KTN) + sce0, Vd + t * 8);                 \
        gl_lds16(Vp + (size_t)srow1 * NS + (KTN) + sce1, Vd + 2048 + t * 8);          \
        __builtin_amdgcn_sched_barrier(0);                                            \
        ATTN_COMPUTE(CUR, BV)                                                         \
        __builtin_amdgcn_sched_barrier(0);                                            \
        _Pragma("unroll") for (int n = 0; n < 4; ++n)                                 \
            BV[n] = *(const float4*)(Bp + (KTN) + 64 + n * 16);                       \
        __builtin_amdgcn_sched_barrier(0);                                            \
        asm volatile("s_waitcnt vmcnt(4)" ::: "memory");                              \
        __builtin_amdgcn_sched_barrier(0);                                            \
        __builtin_amdgcn_s_barrier();                                                 \
        __builtin_amdgcn_sched_barrier(0);                                            \
    }

    // -------- main loop: tiles 0..29, unrolled x2 for static bias-set naming --------
    for (int it = 0; it < 15; ++it) {
        const int tt = it * 2;
        TILESTEP(0, bvA, (tt + 1) * 64)
        TILESTEP(1, bvB, (tt + 2) * 64)
    }

    // -------- tile 30: stage tile 31, full drain at barrier --------
    {
        const int ktn = 31 * 64;
        bf16* Kd = &Kls[1][0];
        bf16* Vd = &Vls[1][0];
        gl_lds16(Kp + (size_t)(ktn + srow0) * HD + sce0, Kd + t * 8);
        gl_lds16(Kp + (size_t)(ktn + srow1) * HD + sce1, Kd + 2048 + t * 8);
        gl_lds16(Vp + (size_t)srow0 * NS + ktn + sce0, Vd + t * 8);
        gl_lds16(Vp + (size_t)srow1 * NS + ktn + sce1, Vd + 2048 + t * 8);
        __builtin_amdgcn_sched_barrier(0);
        ATTN_COMPUTE(0, bvA)
        __builtin_amdgcn_sched_barrier(0);
        asm volatile("s_waitcnt vmcnt(0)" ::: "memory");
        __builtin_amdgcn_sched_barrier(0);
        __builtin_amdgcn_s_barrier();
        __builtin_amdgcn_sched_barrier(0);
    }
    // -------- tile 31: compute only --------
    ATTN_COMPUTE(1, bvB)
#undef TILESTEP
#undef ATTN_COMPUTE

    // rowsum for q = qw + (lane&15): reduce over the 4 lh-groups
    rowsum += __shfl_xor(rowsum, 16, 64);
    rowsum += __shfl_xor(rowsum, 32, 64);
    // redistribute: output rows are q = qw + lh*4 + i (held at lane lh*4+i)
    float inv[4];
#pragma unroll
    for (int i = 0; i < 4; ++i) inv[i] = 1.0f / __shfl(rowsum, lh * 4 + i, 64);

    const int b = bh >> 4, h = bh & 15;
#pragma unroll
    for (int n = 0; n < 4; ++n) {
#pragma unroll
        for (int i = 0; i < 4; ++i) {
            const int qrow = qw + lh * 4 + i;
            valsb[(size_t)(b * NS + qrow) * NE + h * HD + n * 16 + lr] =
                __float2bfloat16(acc_o[n][i] * inv[i]);
        }
    }
}

// ---------------- out GEMM: 64x64 tiles, grid (64,16) = 1024 blocks = 4/CU ----------------
__global__ __launch_bounds__(256, 4) void out_gemm(const bf16* __restrict__ A,
                                                   const bf16* __restrict__ Bm,
                                                   const float* __restrict__ bo,
                                                   float* __restrict__ out) {
    __shared__ bf16 As[64 * 32];
    __shared__ bf16 Bs[64 * 32];
    const int brow = blockIdx.x * 64;
    const int bcol = blockIdx.y * 64;
    const int t = threadIdx.x;
    const int w = t >> 6, lane = t & 63;
    const int wr = (w >> 1) * 32, wc = (w & 1) * 32;
    const int lr = lane & 15, lh = lane >> 4;
    const int K = 1024;

    f32x4 acc[2][2];
#pragma unroll
    for (int m = 0; m < 2; ++m)
#pragma unroll
        for (int n = 0; n < 2; ++n) acc[m][n] = (f32x4){0.f, 0.f, 0.f, 0.f};

    const bf16* ga0 = A + (size_t)(brow + (t >> 2)) * K + (t & 3) * 8;
    const bf16* gb0 = Bm + (size_t)(bcol + (t >> 2)) * K + (t & 3) * 8;
    bf16* la0 = As + t * 8;
    bf16* lb0 = Bs + t * 8;

    for (int kt = 0; kt < K; kt += 32) {
        gl_lds16(ga0 + kt, la0);
        gl_lds16(gb0 + kt, lb0);
        __syncthreads();
        bf16x8 af[2], bfv[2];
#pragma unroll
        for (int m = 0; m < 2; ++m) af[m] = ldv8(&As[(wr + m * 16 + lr) * 32 + lh * 8]);
#pragma unroll
        for (int n = 0; n < 2; ++n) bfv[n] = ldv8(&Bs[(wc + n * 16 + lr) * 32 + lh * 8]);
#pragma unroll
        for (int m = 0; m < 2; ++m)
#pragma unroll
            for (int n = 0; n < 2; ++n) acc[m][n] = MFMA16(af[m], bfv[n], acc[m][n]);
        __syncthreads();
    }

#pragma unroll
    for (int n = 0; n < 2; ++n) {
        const int col = bcol + wc + n * 16 + lr;
        const float bv = bo[col];
#pragma unroll
        for (int m = 0; m < 2; ++m) {
            const int row0 = brow + wr + m * 16 + lh * 4;
#pragma unroll
            for (int i = 0; i < 4; ++i) out[(size_t)(row0 + i) * NE + col] = acc[m][n][i] + bv;
        }
    }
}

extern "C" void kernel_launch(void* const* d_in, const int* in_sizes, int n_in,
                              void* d_out, int out_size, void* d_ws, size_t ws_size,
                              hipStream_t stream) {
    const float* x = (const float*)d_in[0];
    const float* attn_bias = (const float*)d_in[1];
    const float* Wqkv = (const float*)d_in[2];
    const float* bqkv = (const float*)d_in[3];
    const float* Wo = (const float*)d_in[4];
    const float* bo = (const float*)d_in[5];
    float* out = (float*)d_out;

    char* ws = (char*)d_ws;
    bf16* xb = (bf16*)(ws);                      // 8 MiB  [4096,1024]
    bf16* Wqkvb = (bf16*)(ws + (8u << 20));      // 6 MiB  [3072,1024]
    bf16* Wob = (bf16*)(ws + (14u << 20));       // 2 MiB  [1024,1024]
    bf16* Qb = (bf16*)(ws + (16u << 20));        // 8 MiB  [B,H,S,HD]
    bf16* Kb = (bf16*)(ws + (24u << 20));        // 8 MiB  [B,H,S,HD]
    bf16* Vtb = (bf16*)(ws + (32u << 20));       // 8 MiB  [B,H,HD,S]
    bf16* valsb = (bf16*)(ws + (40u << 20));     // 8 MiB  [B,S,H,HD]

    // merged casts (1 launch)
    cast3_k<<<8192, 256, 0, stream>>>(x, Wqkv, Wo, xb, Wqkvb, Wob);

    // QKV projection
    qkv_gemm<<<dim3(32, 24), 256, 0, stream>>>(xb, Wqkvb, bqkv, Qb, Kb, Vtb);

    // fused attention (1-D grid, XCD swizzle inside)
    attn_k<<<dim3(1024), 256, 0, stream>>>(Qb, Kb, Vtb, attn_bias, valsb);

    // output projection
    out_gemm<<<dim3(64, 16), 256, 0, stream>>>(valsb, Wob, bo, out);
}